// Round 1
// baseline (122.381 us; speedup 1.0000x reference)
//
#include <hip/hip_runtime.h>

#define N_SENT 1024
#define LSEQ   128
#define HDIM   768
#define KSPAN  5
#define TPB    192   // HDIM / 4 float4 lanes

__global__ __launch_bounds__(TPB) void bert_pool_kernel(
    const float* __restrict__ review_feat,   // [N, L, H]
    const float* __restrict__ reply_feat,    // [N, L, H]
    const int*   __restrict__ review_nt,     // [N]
    const int*   __restrict__ reply_nt,      // [N]
    const int*   __restrict__ review_ss,     // [N, K]
    const int*   __restrict__ review_se,     // [N, K]
    const int*   __restrict__ reply_ss,      // [N, K]
    const int*   __restrict__ reply_se,      // [N, K]
    float*       __restrict__ out)           // [4, N, H]: review_pt, review_sent, reply_pt, reply_sent
{
    const int n   = blockIdx.x;
    const int tid = threadIdx.x;
    const bool is_reply = (blockIdx.y != 0);

    const float* feat = is_reply ? reply_feat : review_feat;
    const int*   ntp  = is_reply ? reply_nt   : review_nt;
    const int*   ssp  = is_reply ? reply_ss   : review_ss;
    const int*   sep  = is_reply ? reply_se   : review_se;
    float* out_pt   = out + (is_reply ? 2 : 0) * (size_t)N_SENT * HDIM;
    float* out_sent = out + (is_reply ? 3 : 1) * (size_t)N_SENT * HDIM;

    const int nt = ntp[n];

    int s[KSPAN], e[KSPAN];
    int l_lo = 1, l_hi = nt;
#pragma unroll
    for (int k = 0; k < KSPAN; ++k) {
        s[k] = ssp[(size_t)n * KSPAN + k];
        e[k] = sep[(size_t)n * KSPAN + k];
        if (s[k] <= e[k]) {              // valid span
            if (s[k] < l_lo) l_lo = s[k];
            if (e[k] > l_hi) l_hi = e[k];
        }
    }
    if (l_lo < 0) l_lo = 0;
    if (l_hi > LSEQ - 1) l_hi = LSEQ - 1;

    const float4* frow = (const float4*)(feat + (size_t)n * LSEQ * HDIM);

    float sx = 0.f, sy = 0.f, sz = 0.f, sw = 0.f;   // sentence accum
    float px = 0.f, py = 0.f, pz = 0.f, pw = 0.f;   // span accum
    int span_cnt = 0;

    for (int l = l_lo; l <= l_hi; ++l) {
        const bool in_sent = (l >= 1) && (l <= nt);
        bool in_span = false;
#pragma unroll
        for (int k = 0; k < KSPAN; ++k)
            in_span = in_span || ((l >= s[k]) && (l <= e[k]));
        if (!in_sent && !in_span) continue;

        float4 v = frow[(size_t)l * (HDIM / 4) + tid];
        if (in_sent) { sx += v.x; sy += v.y; sz += v.z; sw += v.w; }
        if (in_span) { px += v.x; py += v.y; pz += v.z; pw += v.w; span_cnt++; }
    }

    // sentence mean: count of positions p with 1 <= p <= nt, p < L
    const float sent_cnt = (float)(nt < LSEQ - 1 ? nt : LSEQ - 1);
    const float inv_s = 1.0f / sent_cnt;
    const float smx = sx * inv_s, smy = sy * inv_s, smz = sz * inv_s, smw = sw * inv_s;

    const bool has_span = (span_cnt > 0);
    const float inv_p = 1.0f / fmaxf((float)span_cnt, 1.0f);
    const float ptx = has_span ? px * inv_p : smx;
    const float pty = has_span ? py * inv_p : smy;
    const float ptz = has_span ? pz * inv_p : smz;
    const float ptw = has_span ? pw * inv_p : smw;

    float4* opt = (float4*)(out_pt   + (size_t)n * HDIM);
    float4* osn = (float4*)(out_sent + (size_t)n * HDIM);
    opt[tid] = make_float4(ptx, pty, ptz, ptw);
    osn[tid] = make_float4(smx, smy, smz, smw);
}

extern "C" void kernel_launch(void* const* d_in, const int* in_sizes, int n_in,
                              void* d_out, int out_size, void* d_ws, size_t ws_size,
                              hipStream_t stream) {
    const float* review_feat = (const float*)d_in[0];
    const float* reply_feat  = (const float*)d_in[1];
    const int*   review_nt   = (const int*)d_in[2];
    const int*   reply_nt    = (const int*)d_in[3];
    const int*   review_ss   = (const int*)d_in[4];
    const int*   review_se   = (const int*)d_in[5];
    const int*   reply_ss    = (const int*)d_in[6];
    const int*   reply_se    = (const int*)d_in[7];
    float* out = (float*)d_out;

    dim3 grid(N_SENT, 2);
    bert_pool_kernel<<<grid, TPB, 0, stream>>>(
        review_feat, reply_feat, review_nt, reply_nt,
        review_ss, review_se, reply_ss, reply_se, out);
}

// Round 2
// 101.207 us; speedup vs baseline: 1.2092x; 1.2092x over previous
//
#include <hip/hip_runtime.h>

#define N_SENT 1024
#define LSEQ   128
#define HDIM   768
#define KSPAN  5
#define TPB    192   // HDIM / 4 float4 lanes
#define UNROLL 8

__global__ __launch_bounds__(TPB) void bert_pool_kernel(
    const float* __restrict__ review_feat,   // [N, L, H]
    const float* __restrict__ reply_feat,    // [N, L, H]
    const int*   __restrict__ review_nt,     // [N]
    const int*   __restrict__ reply_nt,      // [N]
    const int*   __restrict__ review_ss,     // [N, K]
    const int*   __restrict__ review_se,     // [N, K]
    const int*   __restrict__ reply_ss,      // [N, K]
    const int*   __restrict__ reply_se,      // [N, K]
    float*       __restrict__ out)           // [4, N, H]: review_pt, review_sent, reply_pt, reply_sent
{
    const int n   = blockIdx.x;
    const int tid = threadIdx.x;
    const bool is_reply = (blockIdx.y != 0);

    const float* feat = is_reply ? reply_feat : review_feat;
    const int*   ntp  = is_reply ? reply_nt   : review_nt;
    const int*   ssp  = is_reply ? reply_ss   : review_ss;
    const int*   sep  = is_reply ? reply_se   : review_se;
    float* out_pt   = out + (is_reply ? 2 : 0) * (size_t)N_SENT * HDIM;
    float* out_sent = out + (is_reply ? 3 : 1) * (size_t)N_SENT * HDIM;

    const int nt = ntp[n];

    int s[KSPAN], e[KSPAN];
    int l_lo = 1, l_hi = nt;
#pragma unroll
    for (int k = 0; k < KSPAN; ++k) {
        s[k] = ssp[(size_t)n * KSPAN + k];
        e[k] = sep[(size_t)n * KSPAN + k];
        if (s[k] <= e[k]) {              // valid span
            if (s[k] < l_lo) l_lo = s[k];
            if (e[k] > l_hi) l_hi = e[k];
        }
    }
    if (l_lo < 0) l_lo = 0;
    if (l_hi > LSEQ - 1) l_hi = LSEQ - 1;

    const float4* frow = (const float4*)(feat + (size_t)n * LSEQ * HDIM);

    float sx = 0.f, sy = 0.f, sz = 0.f, sw = 0.f;   // sentence accum
    float px = 0.f, py = 0.f, pz = 0.f, pw = 0.f;   // span accum
    float span_cnt = 0.f;

    for (int l0 = l_lo; l0 <= l_hi; l0 += UNROLL) {
        float4 v[UNROLL];
        float  ms[UNROLL], mp[UNROLL];
#pragma unroll
        for (int i = 0; i < UNROLL; ++i) {
            const int l    = l0 + i;
            const bool live = (l <= l_hi);
            const int  lc   = live ? l : l_hi;           // clamped dup -> L1 hit
            v[i] = frow[(size_t)lc * (HDIM / 4) + tid];
            ms[i] = (live && l >= 1 && l <= nt) ? 1.0f : 0.0f;
            bool insp = false;
#pragma unroll
            for (int k = 0; k < KSPAN; ++k)
                insp = insp || ((l >= s[k]) && (l <= e[k]));
            mp[i] = (live && insp) ? 1.0f : 0.0f;
        }
#pragma unroll
        for (int i = 0; i < UNROLL; ++i) {
            sx = fmaf(v[i].x, ms[i], sx);
            sy = fmaf(v[i].y, ms[i], sy);
            sz = fmaf(v[i].z, ms[i], sz);
            sw = fmaf(v[i].w, ms[i], sw);
            px = fmaf(v[i].x, mp[i], px);
            py = fmaf(v[i].y, mp[i], py);
            pz = fmaf(v[i].z, mp[i], pz);
            pw = fmaf(v[i].w, mp[i], pw);
            span_cnt += mp[i];
        }
    }

    // sentence mean: count of positions p with 1 <= p <= nt, p < L
    const float sent_cnt = (float)(nt < LSEQ - 1 ? nt : LSEQ - 1);
    const float inv_s = 1.0f / sent_cnt;
    const float smx = sx * inv_s, smy = sy * inv_s, smz = sz * inv_s, smw = sw * inv_s;

    const bool has_span = (span_cnt > 0.5f);
    const float inv_p = 1.0f / fmaxf(span_cnt, 1.0f);
    const float ptx = has_span ? px * inv_p : smx;
    const float pty = has_span ? py * inv_p : smy;
    const float ptz = has_span ? pz * inv_p : smz;
    const float ptw = has_span ? pw * inv_p : smw;

    float4* opt = (float4*)(out_pt   + (size_t)n * HDIM);
    float4* osn = (float4*)(out_sent + (size_t)n * HDIM);
    opt[tid] = make_float4(ptx, pty, ptz, ptw);
    osn[tid] = make_float4(smx, smy, smz, smw);
}

extern "C" void kernel_launch(void* const* d_in, const int* in_sizes, int n_in,
                              void* d_out, int out_size, void* d_ws, size_t ws_size,
                              hipStream_t stream) {
    const float* review_feat = (const float*)d_in[0];
    const float* reply_feat  = (const float*)d_in[1];
    const int*   review_nt   = (const int*)d_in[2];
    const int*   reply_nt    = (const int*)d_in[3];
    const int*   review_ss   = (const int*)d_in[4];
    const int*   review_se   = (const int*)d_in[5];
    const int*   reply_ss    = (const int*)d_in[6];
    const int*   reply_se    = (const int*)d_in[7];
    float* out = (float*)d_out;

    dim3 grid(N_SENT, 2);
    bert_pool_kernel<<<grid, TPB, 0, stream>>>(
        review_feat, reply_feat, review_nt, reply_nt,
        review_ss, review_se, reply_ss, reply_se, out);
}